// Round 4
// baseline (700.542 us; speedup 1.0000x reference)
//
#include <hip/hip_runtime.h>

// UAG_RNN v8: scan-chain latency fixes.
//  - colscan: yl LDS tile removed (ys loaded from global, L2-hit: same column
//    as neighboring wave's yr); reload-after-use register pipeline for pb and
//    yr/ys (no same-step vmcnt waits -- v7's regression); boundary shift term
//    zeroed via per-thread bTr=0 + zero pads (no per-step masking).
//  - rowscan: 64 blocks x 128 threads = 2 independent wave-chains per block
//    (2x memory-level parallelism per CU), private LDS slices, no barriers.
// B=8, C=64, H=128, W=128.

#define B_ 8
#define C_ 64
#define H_ 128
#define W_ 128
#define HW_ (H_*W_)      // 16384
#define CHW_ (C_*HW_)    // 1048576
#define TOT_ (B_*CHW_)   // 8388608

typedef __attribute__((ext_vector_type(8))) short bfrag;
typedef __attribute__((ext_vector_type(4))) float f4_t;

// LDS-ordering barrier: flush own DS ops, then workgroup barrier. Does NOT
// drain vmcnt — global prefetch loads / stores stay in flight across steps.
#define LDS_BARRIER() do { \
    asm volatile("s_waitcnt lgkmcnt(0)" ::: "memory"); \
    __builtin_amdgcn_s_barrier(); \
} while (0)

#define WAVE_LDS_FENCE() asm volatile("s_waitcnt lgkmcnt(0)" ::: "memory")

__device__ inline unsigned short bfr(float f) {
    unsigned int u = __float_as_uint(f);
    u += 0x7fffu + ((u >> 16) & 1u);
    return (unsigned short)(u >> 16);
}
__device__ inline float b2f(unsigned short u) {
    return __uint_as_float(((unsigned int)u) << 16);
}
// HW packed f32->bf16 (RNE, identical to bfr)
__device__ inline unsigned int cvtpk(float lo, float hi) {
    unsigned int r;
    asm("v_cvt_pk_bf16_f32 %0, %1, %2" : "=v"(r) : "v"(lo), "v"(hi));
    return r;
}
__device__ inline bfrag packf(float4 a, float4 b) {
    bfrag r;
    r[0]=(short)bfr(a.x); r[1]=(short)bfr(a.y); r[2]=(short)bfr(a.z); r[3]=(short)bfr(a.w);
    r[4]=(short)bfr(b.x); r[5]=(short)bfr(b.y); r[6]=(short)bfr(b.z); r[7]=(short)bfr(b.w);
    return r;
}
__device__ inline bfrag packfs(float4 a, float4 b, float s) {
    bfrag r;
    r[0]=(short)bfr(s*a.x); r[1]=(short)bfr(s*a.y); r[2]=(short)bfr(s*a.z); r[3]=(short)bfr(s*a.w);
    r[4]=(short)bfr(s*b.x); r[5]=(short)bfr(s*b.y); r[6]=(short)bfr(s*b.z); r[7]=(short)bfr(s*b.w);
    return r;
}
__device__ inline unsigned int relu2(unsigned int w) {
    unsigned int lo = (w & 0x8000u) ? 0u : (w & 0xffffu);
    unsigned int hi = (w & 0x80000000u) ? 0u : (w & 0xffff0000u);
    return lo | hi;
}
__device__ inline uint4 relu8(uint4 v) {
    v.x = relu2(v.x); v.y = relu2(v.y); v.z = relu2(v.z); v.w = relu2(v.w);
    return v;
}
// XOR slot swizzle: rows are 64 shorts (128B) = 8 slots of 16B; swizzle slot
// by (row&7) so a wave's per-lane rows spread across all 8 slots.
__device__ inline int swz(int r, int s) {
    return (((s >> 3) ^ (r & 7)) << 3) | (s & 7);
}

#define MFMA __builtin_amdgcn_mfma_f32_16x16x32_bf16

// x,y NCHW fp32 -> NHWC bf16 (x2 / y2b)
__global__ void k_prep(const float* __restrict__ x, const float* __restrict__ y,
                       unsigned short* __restrict__ y2b, unsigned short* __restrict__ x2) {
    __shared__ float t[64][65];
    int blk = blockIdx.x;
    int isx = blk >> 11; blk &= 2047;
    int b = blk >> 8, hw0 = (blk & 255) * 64;
    int cq = threadIdx.x >> 6, lo = threadIdx.x & 63;
    const float* ip = (isx ? x : y) + (size_t)b * CHW_;
#pragma unroll
    for (int p = 0; p < 16; p++) {
        int c = p * 4 + cq;
        t[c][lo] = ip[(size_t)c * HW_ + hw0 + lo];
    }
    __syncthreads();
    unsigned short* op = (isx ? x2 : y2b) + (size_t)b * CHW_;
#pragma unroll
    for (int p = 0; p < 16; p++) {
        int hw = p * 4 + cq;
        op[(size_t)(hw0 + hw) * 64 + lo] = bfr(t[lo][hw]);
    }
}

// sum 4 bf16 NHWC dir buffers -> out NCHW fp32
__global__ void k_tb(const unsigned short* __restrict__ i0, const unsigned short* __restrict__ i1,
                     const unsigned short* __restrict__ i2, const unsigned short* __restrict__ i3,
                     float* __restrict__ outp) {
    __shared__ float t[64][65];
    int blk = blockIdx.x;
    int b = blk >> 8, hw0 = (blk & 255) * 64;
    int tid = threadIdx.x;
    size_t bb = (size_t)b * CHW_;
    int hwi = tid >> 4, c4 = (tid & 15) * 4;
#pragma unroll
    for (int p = 0; p < 4; p++) {
        int hw = p * 16 + hwi;
        size_t s = bb + (size_t)(hw0 + hw) * 64 + c4;
        uint2 u0 = *(const uint2*)(i0 + s);
        uint2 u1 = *(const uint2*)(i1 + s);
        uint2 u2 = *(const uint2*)(i2 + s);
        uint2 u3 = *(const uint2*)(i3 + s);
        float v0 = b2f((unsigned short)(u0.x & 0xffffu)) + b2f((unsigned short)(u1.x & 0xffffu))
                 + b2f((unsigned short)(u2.x & 0xffffu)) + b2f((unsigned short)(u3.x & 0xffffu));
        float v1 = b2f((unsigned short)(u0.x >> 16)) + b2f((unsigned short)(u1.x >> 16))
                 + b2f((unsigned short)(u2.x >> 16)) + b2f((unsigned short)(u3.x >> 16));
        float v2 = b2f((unsigned short)(u0.y & 0xffffu)) + b2f((unsigned short)(u1.y & 0xffffu))
                 + b2f((unsigned short)(u2.y & 0xffffu)) + b2f((unsigned short)(u3.y & 0xffffu));
        float v3 = b2f((unsigned short)(u0.y >> 16)) + b2f((unsigned short)(u1.y >> 16))
                 + b2f((unsigned short)(u2.y >> 16)) + b2f((unsigned short)(u3.y >> 16));
        t[hw][c4 + 0] = v0; t[hw][c4 + 1] = v1; t[hw][c4 + 2] = v2; t[hw][c4 + 3] = v3;
    }
    __syncthreads();
    float* op = outp + bb;
    int cq = tid >> 6, lo = tid & 63;
#pragma unroll
    for (int p = 0; p < 16; p++) {
        int c = p * 4 + cq;
        op[(size_t)c * HW_ + hw0 + lo] = t[lo][c];
    }
}

// Row scans: 64 blocks x 128 threads = 2 independent wave-chains per block.
// Wave task t = bid*2 + wave: s = t>>6, b = (t>>3)&7, wb = t&7.
__global__ __launch_bounds__(128) void k_rowscan(
        const unsigned short* __restrict__ x2, const unsigned short* __restrict__ y2b,
        const float* __restrict__ Wc, const float* __restrict__ bc,
        unsigned short* __restrict__ hs2, unsigned short* __restrict__ hn2) {
    int tid = threadIdx.x;
    int wave = tid >> 6;
    int t = blockIdx.x * 2 + wave;
    int s = t >> 6, b = (t >> 3) & 7, wb = t & 7;
    int w0 = wb * 16;
    int lane = tid & 63, q = lane >> 4, n = lane & 15;
    int ka = s ? 8 : 0, kb = ka + 1;

    bfrag WaF[4][2], WbF[4][2];
#pragma unroll
    for (int mt = 0; mt < 4; mt++)
#pragma unroll
        for (int kc = 0; kc < 2; kc++) {
            const float* wp = Wc + (size_t)(ka * 64 + mt * 16 + n) * 64 + kc * 32 + q * 8;
            WaF[mt][kc] = packf(*(const float4*)wp, *(const float4*)(wp + 4));
            const float* wq2 = Wc + (size_t)(kb * 64 + mt * 16 + n) * 64 + kc * 32 + q * 8;
            WbF[mt][kc] = packf(*(const float4*)wq2, *(const float4*)(wq2 + 4));
        }
    f4_t baR[4], bbR[4];
#pragma unroll
    for (int mt = 0; mt < 4; mt++) {
        float4 ta = *(const float4*)&bc[ka * 64 + mt * 16 + q * 4];
        float4 tb = *(const float4*)&bc[kb * 64 + mt * 16 + q * 4];
        baR[mt] = f4_t{ta.x, ta.y, ta.z, ta.w};
        bbR[mt] = f4_t{tb.x, tb.y, tb.z, tb.w};
    }

    const unsigned short* xb = x2 + (size_t)b * CHW_;
    const unsigned short* yb = y2b + (size_t)b * CHW_;
    unsigned short* dT = (s ? hn2 : hs2) + (size_t)b * CHW_;

    __shared__ __align__(16) unsigned short stt[2][2][16][72];  // [wave][buf]

    int row0 = s ? 127 : 0;
    {
        const unsigned short* sp = xb + (size_t)(row0 * 128 + w0 + n) * 64 + q * 16;
        uint4 v0 = *(const uint4*)sp;
        uint4 v1 = *(const uint4*)(sp + 8);
        if (s) { v0 = relu8(v0); v1 = relu8(v1); }
        *(uint4*)&stt[wave][0][n][q * 16] = v0;
        *(uint4*)&stt[wave][0][n][q * 16 + 8] = v1;
        unsigned short* op = dT + (size_t)(row0 * 128 + w0 + n) * 64 + q * 16;
        *(uint4*)op = v0;
        *(uint4*)(op + 8) = v1;
    }

    // prefetch i=1
    uint4 xf0, xf1; ushort4 yv[4];
    {
        int row1 = s ? 126 : 1;
        const unsigned short* sp = xb + (size_t)(row1 * 128 + w0 + n) * 64 + q * 8;
        xf0 = *(const uint4*)sp;
        xf1 = *(const uint4*)(sp + 32);
#pragma unroll
        for (int mt = 0; mt < 4; mt++)
            yv[mt] = *(const ushort4*)&yb[(size_t)(row0 * 128 + w0 + n) * 64 + mt * 16 + q * 4];
    }
    WAVE_LDS_FENCE();

    for (int i = 1; i < 128; i++) {
        int row = s ? 127 - i : i;
        int rd = (i - 1) & 1, wr = i & 1;

        bfrag fb0 = *(const bfrag*)&stt[wave][rd][n][q * 8];
        bfrag fb1 = *(const bfrag*)&stt[wave][rd][n][32 + q * 8];
        bfrag fa0 = *(const bfrag*)&xf0;
        bfrag fa1 = *(const bfrag*)&xf1;

        f4_t DA[4], DB[4];
#pragma unroll
        for (int mt = 0; mt < 4; mt++) {
            DA[mt] = MFMA(WaF[mt][0], fa0, baR[mt], 0, 0, 0);
            DA[mt] = MFMA(WaF[mt][1], fa1, DA[mt], 0, 0, 0);
            DB[mt] = MFMA(WbF[mt][0], fb0, bbR[mt], 0, 0, 0);
            DB[mt] = MFMA(WbF[mt][1], fb1, DB[mt], 0, 0, 0);
        }

        // reload x for i+1 right after consumption (full-step slack)
        if (i < 127) {
            int rowN = s ? 127 - (i + 1) : i + 1;
            const unsigned short* sp = xb + (size_t)(rowN * 128 + w0 + n) * 64 + q * 8;
            xf0 = *(const uint4*)sp;
            xf1 = *(const uint4*)(sp + 32);
        }

#pragma unroll
        for (int mt = 0; mt < 4; mt++) {
            float h0 = fmaxf(fmaf(DB[mt][0], b2f(yv[mt].x), DA[mt][0]), 0.f);
            float h1 = fmaxf(fmaf(DB[mt][1], b2f(yv[mt].y), DA[mt][1]), 0.f);
            float h2 = fmaxf(fmaf(DB[mt][2], b2f(yv[mt].z), DA[mt][2]), 0.f);
            float h3 = fmaxf(fmaf(DB[mt][3], b2f(yv[mt].w), DA[mt][3]), 0.f);
            uint2 pk; pk.x = cvtpk(h0, h1); pk.y = cvtpk(h2, h3);
            *(uint2*)&stt[wave][wr][n][mt * 16 + q * 4] = pk;
            *(uint2*)&dT[(size_t)(row * 128 + w0 + n) * 64 + mt * 16 + q * 4] = pk;
        }

        // reload y for i+1 right after consumption
        if (i < 127) {
            int rowN = s ? 127 - (i + 1) : i + 1;
            int yrowN = s ? rowN + 1 : rowN - 1;
#pragma unroll
            for (int mt = 0; mt < 4; mt++)
                yv[mt] = *(const ushort4*)&yb[(size_t)(yrowN * 128 + w0 + n) * 64 + mt * 16 + q * 4];
        }
        WAVE_LDS_FENCE();
    }
}

// Col scans: grid 32 = d(4) x b(8). 512 threads = 8 waves.
// State in XOR-swizzled 128B-stride LDS (double-buffered, 1 barrier/step);
// yr AND ys from global (ys is an L2 hit: same column fetched by the
// neighboring wave); reload-after-use pipeline; boundary shift term killed
// via per-thread bTr=0 + zero pads (zero per-step cost).
__global__ __launch_bounds__(512, 2) void k_colscan(
        const unsigned short* __restrict__ y2b,
        const unsigned short* __restrict__ hs2, const unsigned short* __restrict__ hn2,
        const float* __restrict__ Wc, const float* __restrict__ bc,
        const float* __restrict__ gam,
        unsigned short* __restrict__ outD) {
    int bid = blockIdx.x;
    int d = bid >> 3, b = bid & 7;
    int tid = threadIdx.x;
    int wave = tid >> 6, lane = tid & 63, q = lane >> 4, n = lane & 15;
    int row = wave * 16 + n;
    int down = (d < 2) ? 1 : 0;
    int flip = d & 1;
    const unsigned short* base2 = ((d < 2) ? hs2 : hn2) + (size_t)b * CHW_;
    int kt, ka, kb;
    if (d == 0)      { kt = 2;  ka = 3;  kb = 4;  }
    else if (d == 1) { kt = 5;  ka = 6;  kb = 7;  }
    else if (d == 2) { kt = 10; ka = 11; kb = 12; }
    else             { kt = 13; ka = 14; kb = 15; }
    float g = gam[d];

    bfrag WA[4][2], WB[4][2], WT[4][2];
#pragma unroll
    for (int mt = 0; mt < 4; mt++)
#pragma unroll
        for (int kc = 0; kc < 2; kc++) {
            const float* wa = Wc + (size_t)(ka * 64 + mt * 16 + n) * 64 + kc * 32 + q * 8;
            const float* wb = Wc + (size_t)(kb * 64 + mt * 16 + n) * 64 + kc * 32 + q * 8;
            const float* wt = Wc + (size_t)(kt * 64 + mt * 16 + n) * 64 + kc * 32 + q * 8;
            WA[mt][kc] = packf(*(const float4*)wa, *(const float4*)(wa + 4));
            WB[mt][kc] = packf(*(const float4*)wb, *(const float4*)(wb + 4));
            // gamma folded into WT (gamma = 0.5 -> exact scaling)
            WT[mt][kc] = packfs(*(const float4*)wt, *(const float4*)(wt + 4), g);
        }
    // boundary rows: output lanes for H-row r are exactly the threads with
    // row==r (C/D col = lane&15 within wave); zeroing their bTr + the zeroed
    // ft pads makes DT==0 there -> shift term vanishes, no runtime masking.
    bool bz = down ? (row == 0) : (row == 127);
    f4_t bAr[4], bBr[4], bTr[4];
#pragma unroll
    for (int mt = 0; mt < 4; mt++) {
        float4 ta = *(const float4*)&bc[ka * 64 + mt * 16 + q * 4];
        float4 tb = *(const float4*)&bc[kb * 64 + mt * 16 + q * 4];
        float4 tt = *(const float4*)&bc[kt * 64 + mt * 16 + q * 4];
        bAr[mt] = f4_t{ta.x, ta.y, ta.z, ta.w};
        bBr[mt] = f4_t{tb.x, tb.y, tb.z, tb.w};
        float gm = bz ? 0.f : g;
        bTr[mt] = f4_t{gm * tt.x, gm * tt.y, gm * tt.z, gm * tt.w};
    }

    const unsigned short* yB = y2b + (size_t)b * CHW_;
    unsigned short* oB = outD + (size_t)d * TOT_ + (size_t)b * CHW_;

    // 128B-stride rows + XOR slot swizzle; rows 0 and 129 are zero pads.
    __shared__ __align__(16) unsigned short stt[2][130][64];
    for (int idx = tid; idx < 2 * 2 * 64; idx += 512) {
        int buf = idx >> 7, hi = (idx >> 6) & 1, t = idx & 63;
        stt[buf][hi ? 129 : 0][t] = 0;
    }

    // ---- j = 0 : c0 = relu(base col0)
    int c0 = flip ? 127 : 0;
    {
        const unsigned short* sp = base2 + (size_t)(row * 128 + c0) * 64 + q * 16;
        uint4 v0 = relu8(*(const uint4*)sp);
        uint4 v1 = relu8(*(const uint4*)(sp + 8));
        *(uint4*)&stt[0][row + 1][swz(row + 1, q * 16)] = v0;
        *(uint4*)&stt[0][row + 1][swz(row + 1, q * 16 + 8)] = v1;
        unsigned short* op = oB + (size_t)(row * 128 + c0) * 64 + q * 16;
        *(uint4*)op = v0;
        *(uint4*)(op + 8) = v1;
    }

    int srow = down ? row : row + 2;   // shifted-state LDS row (incl. +1 pad)
    int rsh = row + (down ? -1 : 1);
    rsh = rsh < 0 ? 0 : (rsh > 127 ? 127 : rsh);

    // initial loads for step 1: pb = base col c(1); yr/ys = y col yc(1)
    uint4 pb0, pb1; ushort4 yru[4], ysu[4];
    {
        int c1 = flip ? 126 : 1;
        const unsigned short* sp = base2 + (size_t)(row * 128 + c1) * 64 + q * 8;
        pb0 = *(const uint4*)sp;
        pb1 = *(const uint4*)(sp + 32);
        int yc1 = flip ? 127 : 0;
#pragma unroll
        for (int mt = 0; mt < 4; mt++) {
            yru[mt] = *(const ushort4*)&yB[(size_t)(row * 128 + yc1) * 64 + mt * 16 + q * 4];
            ysu[mt] = *(const ushort4*)&yB[(size_t)(rsh * 128 + yc1) * 64 + mt * 16 + q * 4];
        }
    }
    LDS_BARRIER();

    for (int j = 1; j < 128; j++) {
        int cj = flip ? 127 - j : j;
        int rd = (j - 1) & 1, wr = j & 1;

        // LDS reads: state frags (own row + shifted row)
        bfrag fb0 = *(const bfrag*)&stt[rd][row + 1][swz(row + 1, q * 8)];
        bfrag fb1 = *(const bfrag*)&stt[rd][row + 1][swz(row + 1, 32 + q * 8)];
        bfrag ft0 = *(const bfrag*)&stt[rd][srow][swz(srow, q * 8)];
        bfrag ft1 = *(const bfrag*)&stt[rd][srow][swz(srow, 32 + q * 8)];
        bfrag fa0 = *(const bfrag*)&pb0;
        bfrag fa1 = *(const bfrag*)&pb1;

        f4_t DA[4], DB[4], DT[4];
#pragma unroll
        for (int mt = 0; mt < 4; mt++) {
            DA[mt] = MFMA(WA[mt][0], fa0, bAr[mt], 0, 0, 0);
            DA[mt] = MFMA(WA[mt][1], fa1, DA[mt], 0, 0, 0);
            DB[mt] = MFMA(WB[mt][0], fb0, bBr[mt], 0, 0, 0);
            DB[mt] = MFMA(WB[mt][1], fb1, DB[mt], 0, 0, 0);
            DT[mt] = MFMA(WT[mt][0], ft0, bTr[mt], 0, 0, 0);
            DT[mt] = MFMA(WT[mt][1], ft1, DT[mt], 0, 0, 0);
        }

        // reload pb <- base col c(j+1) right after consumption
        if (j < 127) {
            int cN = flip ? 126 - j : j + 1;
            const unsigned short* sp = base2 + (size_t)(row * 128 + cN) * 64 + q * 8;
            pb0 = *(const uint4*)sp;
            pb1 = *(const uint4*)(sp + 32);
        }

        // finalize: h = relu(DA + DB*yr + DT*ys)
#pragma unroll
        for (int mt = 0; mt < 4; mt++) {
            float h0 = fmaxf(fmaf(DT[mt][0], b2f(ysu[mt].x), fmaf(DB[mt][0], b2f(yru[mt].x), DA[mt][0])), 0.f);
            float h1 = fmaxf(fmaf(DT[mt][1], b2f(ysu[mt].y), fmaf(DB[mt][1], b2f(yru[mt].y), DA[mt][1])), 0.f);
            float h2 = fmaxf(fmaf(DT[mt][2], b2f(ysu[mt].z), fmaf(DB[mt][2], b2f(yru[mt].z), DA[mt][2])), 0.f);
            float h3 = fmaxf(fmaf(DT[mt][3], b2f(ysu[mt].w), fmaf(DB[mt][3], b2f(yru[mt].w), DA[mt][3])), 0.f);
            uint2 pk; pk.x = cvtpk(h0, h1); pk.y = cvtpk(h2, h3);
            *(uint2*)&stt[wr][row + 1][swz(row + 1, mt * 16 + q * 4)] = pk;
            *(uint2*)&oB[(size_t)(row * 128 + cj) * 64 + mt * 16 + q * 4] = pk;
        }

        // reload yr/ys <- y col yc(j+1) right after consumption
        if (j < 127) {
            int ycN = flip ? 127 - j : j;
#pragma unroll
            for (int mt = 0; mt < 4; mt++) {
                yru[mt] = *(const ushort4*)&yB[(size_t)(row * 128 + ycN) * 64 + mt * 16 + q * 4];
                ysu[mt] = *(const ushort4*)&yB[(size_t)(rsh * 128 + ycN) * 64 + mt * 16 + q * 4];
            }
        }
        LDS_BARRIER();
    }
}

extern "C" void kernel_launch(void* const* d_in, const int* in_sizes, int n_in,
                              void* d_out, int out_size, void* d_ws, size_t ws_size,
                              hipStream_t stream) {
    const float* x   = (const float*)d_in[0];
    const float* y   = (const float*)d_in[1];
    const float* Wc  = (const float*)d_in[2];
    const float* bc  = (const float*)d_in[3];
    const float* gam = (const float*)d_in[4];
    float* out = (float*)d_out;

    // ws layout (all bf16): x2, y2b, hs2, hn2 (TOT_ each), outD (4x TOT_)
    unsigned short* x2  = (unsigned short*)d_ws;
    unsigned short* y2b = x2 + (size_t)TOT_;
    unsigned short* hs2 = y2b + (size_t)TOT_;
    unsigned short* hn2 = hs2 + (size_t)TOT_;
    unsigned short* outD = hn2 + (size_t)TOT_;

    hipLaunchKernelGGL(k_prep, dim3(4096), dim3(256), 0, stream, x, y, y2b, x2);
    hipLaunchKernelGGL(k_rowscan, dim3(64), dim3(128), 0, stream, x2, y2b, Wc, bc, hs2, hn2);
    hipLaunchKernelGGL(k_colscan, dim3(32), dim3(512), 0, stream, y2b, hs2, hn2, Wc, bc, gam, outD);
    hipLaunchKernelGGL(k_tb, dim3(2048), dim3(256), 0, stream,
                       outD, outD + (size_t)TOT_, outD + 2 * (size_t)TOT_,
                       outD + 3 * (size_t)TOT_, out);
}

// Round 6
// 516.232 us; speedup vs baseline: 1.3570x; 1.3570x over previous
//
#include <hip/hip_runtime.h>

// UAG_RNN v10: v9 + race fix in the scan barrier.
//  - LDS_BARRIER was two separate statements (asm lgkmcnt; builtin s_barrier);
//    the builtin is not an IR memory fence, so LLVM could schedule next-step
//    ds_reads/ds_writes between the waitcnt and the barrier -> cross-wave
//    stale reads of the shifted state row (sporadic, timing-dependent; caught
//    by post-timing replay check). Fix: single fused asm blob
//    "s_waitcnt lgkmcnt(0); s_barrier" + sched_barrier(0) brackets.
//  - everything else identical to v9 (WHC base/y layouts, coalesced 16B
//    loads, swizzled stt dbuf, reload-after-use pipeline, gamma-folded WT).
// B=8, C=64, H=128, W=128.

#define B_ 8
#define C_ 64
#define H_ 128
#define W_ 128
#define HW_ (H_*W_)      // 16384
#define CHW_ (C_*HW_)    // 1048576
#define TOT_ (B_*CHW_)   // 8388608

typedef __attribute__((ext_vector_type(8))) short bfrag;
typedef __attribute__((ext_vector_type(4))) float f4_t;

// Fused LDS-ordering barrier: waitcnt+barrier in ONE asm blob so nothing can
// be scheduled between them; "memory" clobber pins IR-level motion;
// sched_barrier(0) pins machine-scheduler motion of register-only ops.
// Does NOT drain vmcnt -- global prefetch loads/stores stay in flight.
#define LDS_BARRIER() do { \
    __builtin_amdgcn_sched_barrier(0); \
    asm volatile("s_waitcnt lgkmcnt(0)\n\ts_barrier" ::: "memory"); \
    __builtin_amdgcn_sched_barrier(0); \
} while (0)

// Single-wave LDS ordering point (1-wave blocks: HW DS ops are in-order per
// wave; the asm+sched_barrier stops compiler reordering).
#define WAVE_LDS_FENCE() do { \
    asm volatile("s_waitcnt lgkmcnt(0)" ::: "memory"); \
    __builtin_amdgcn_sched_barrier(0); \
} while (0)

__device__ inline unsigned short bfr(float f) {
    unsigned int u = __float_as_uint(f);
    u += 0x7fffu + ((u >> 16) & 1u);
    return (unsigned short)(u >> 16);
}
__device__ inline float b2f(unsigned short u) {
    return __uint_as_float(((unsigned int)u) << 16);
}
__device__ inline float blo(unsigned int u) { return __uint_as_float(u << 16); }
__device__ inline float bhi(unsigned int u) { return __uint_as_float(u & 0xffff0000u); }
// HW packed f32->bf16 (RNE, identical to bfr)
__device__ inline unsigned int cvtpk(float lo, float hi) {
    unsigned int r;
    asm("v_cvt_pk_bf16_f32 %0, %1, %2" : "=v"(r) : "v"(lo), "v"(hi));
    return r;
}
__device__ inline bfrag packf(float4 a, float4 b) {
    bfrag r;
    r[0]=(short)bfr(a.x); r[1]=(short)bfr(a.y); r[2]=(short)bfr(a.z); r[3]=(short)bfr(a.w);
    r[4]=(short)bfr(b.x); r[5]=(short)bfr(b.y); r[6]=(short)bfr(b.z); r[7]=(short)bfr(b.w);
    return r;
}
__device__ inline bfrag packfs(float4 a, float4 b, float s) {
    bfrag r;
    r[0]=(short)bfr(s*a.x); r[1]=(short)bfr(s*a.y); r[2]=(short)bfr(s*a.z); r[3]=(short)bfr(s*a.w);
    r[4]=(short)bfr(s*b.x); r[5]=(short)bfr(s*b.y); r[6]=(short)bfr(s*b.z); r[7]=(short)bfr(s*b.w);
    return r;
}
__device__ inline unsigned int relu2(unsigned int w) {
    unsigned int lo = (w & 0x8000u) ? 0u : (w & 0xffffu);
    unsigned int hi = (w & 0x80000000u) ? 0u : (w & 0xffff0000u);
    return lo | hi;
}
__device__ inline uint4 relu8(uint4 v) {
    v.x = relu2(v.x); v.y = relu2(v.y); v.z = relu2(v.z); v.w = relu2(v.w);
    return v;
}
// XOR slot swizzle for stt (rows of 64 shorts = 8 slots of 16B)
__device__ inline int swz(int r, int s) {
    return (((s >> 3) ^ (r & 7)) << 3) | (s & 7);
}
// channel use-order swizzle for y2t: c = mt*16+q*4+r -> q*16+mt*4+r
__device__ inline int newc(int c) {
    return (((c >> 2) & 3) << 4) | ((c >> 4) << 2) | (c & 3);
}

#define MFMA __builtin_amdgcn_mfma_f32_16x16x32_bf16

// x NCHW fp32 -> x2 NHWC bf16; y NCHW fp32 -> y2b NHWC bf16 + y2t WHC-swz bf16
__global__ void k_prep(const float* __restrict__ x, const float* __restrict__ y,
                       unsigned short* __restrict__ y2b, unsigned short* __restrict__ x2,
                       unsigned short* __restrict__ y2t) {
    __shared__ float t[64][65];
    int blk = blockIdx.x;
    int isx = blk >> 11; blk &= 2047;
    int b = blk >> 8, hw0 = (blk & 255) * 64;
    int cq = threadIdx.x >> 6, lo = threadIdx.x & 63;
    const float* ip = (isx ? x : y) + (size_t)b * CHW_;
#pragma unroll
    for (int p = 0; p < 16; p++) {
        int c = p * 4 + cq;
        t[c][lo] = ip[(size_t)c * HW_ + hw0 + lo];
    }
    __syncthreads();
    unsigned short* op = (isx ? x2 : y2b) + (size_t)b * CHW_;
#pragma unroll
    for (int p = 0; p < 16; p++) {
        int hw = p * 4 + cq;
        op[(size_t)(hw0 + hw) * 64 + lo] = bfr(t[lo][hw]);
    }
    if (!isx) {
        unsigned short* op2 = y2t + (size_t)b * CHW_;
        int lon = newc(lo);
#pragma unroll
        for (int p = 0; p < 16; p++) {
            int hw = p * 4 + cq;
            int pos = hw0 + hw, h = pos >> 7, w = pos & 127;
            op2[(size_t)w * 8192 + h * 64 + lon] = bfr(t[lo][hw]);
        }
    }
}

// sum 4 bf16 NHWC dir buffers -> out NCHW fp32
__global__ void k_tb(const unsigned short* __restrict__ i0, const unsigned short* __restrict__ i1,
                     const unsigned short* __restrict__ i2, const unsigned short* __restrict__ i3,
                     float* __restrict__ outp) {
    __shared__ float t[64][65];
    int blk = blockIdx.x;
    int b = blk >> 8, hw0 = (blk & 255) * 64;
    int tid = threadIdx.x;
    size_t bb = (size_t)b * CHW_;
    int hwi = tid >> 4, c4 = (tid & 15) * 4;
#pragma unroll
    for (int p = 0; p < 4; p++) {
        int hw = p * 16 + hwi;
        size_t s = bb + (size_t)(hw0 + hw) * 64 + c4;
        uint2 u0 = *(const uint2*)(i0 + s);
        uint2 u1 = *(const uint2*)(i1 + s);
        uint2 u2 = *(const uint2*)(i2 + s);
        uint2 u3 = *(const uint2*)(i3 + s);
        float v0 = blo(u0.x) + blo(u1.x) + blo(u2.x) + blo(u3.x);
        float v1 = bhi(u0.x) + bhi(u1.x) + bhi(u2.x) + bhi(u3.x);
        float v2 = blo(u0.y) + blo(u1.y) + blo(u2.y) + blo(u3.y);
        float v3 = bhi(u0.y) + bhi(u1.y) + bhi(u2.y) + bhi(u3.y);
        t[hw][c4 + 0] = v0; t[hw][c4 + 1] = v1; t[hw][c4 + 2] = v2; t[hw][c4 + 3] = v3;
    }
    __syncthreads();
    float* op = outp + bb;
    int cq = tid >> 6, lo = tid & 63;
#pragma unroll
    for (int p = 0; p < 16; p++) {
        int c = p * 4 + cq;
        op[(size_t)c * HW_ + hw0 + lo] = t[lo][c];
    }
}

// Row scans: grid 128 = s(2) x b(8) x wb(8 of width 16). 1 wave/block.
// dT written in [W][H][C] layout for colscan.
__global__ __launch_bounds__(64) void k_rowscan(
        const unsigned short* __restrict__ x2, const unsigned short* __restrict__ y2b,
        const float* __restrict__ Wc, const float* __restrict__ bc,
        unsigned short* __restrict__ hs2, unsigned short* __restrict__ hn2) {
    int bid = blockIdx.x;
    int s = bid >> 6, b = (bid >> 3) & 7, wb = bid & 7;
    int w0 = wb * 16;
    int lane = threadIdx.x, q = lane >> 4, n = lane & 15;
    int ka = s ? 8 : 0, kb = ka + 1;

    bfrag WaF[4][2], WbF[4][2];
#pragma unroll
    for (int mt = 0; mt < 4; mt++)
#pragma unroll
        for (int kc = 0; kc < 2; kc++) {
            const float* wp = Wc + (size_t)(ka * 64 + mt * 16 + n) * 64 + kc * 32 + q * 8;
            WaF[mt][kc] = packf(*(const float4*)wp, *(const float4*)(wp + 4));
            const float* wq2 = Wc + (size_t)(kb * 64 + mt * 16 + n) * 64 + kc * 32 + q * 8;
            WbF[mt][kc] = packf(*(const float4*)wq2, *(const float4*)(wq2 + 4));
        }
    f4_t baR[4], bbR[4];
#pragma unroll
    for (int mt = 0; mt < 4; mt++) {
        float4 ta = *(const float4*)&bc[ka * 64 + mt * 16 + q * 4];
        float4 tb = *(const float4*)&bc[kb * 64 + mt * 16 + q * 4];
        baR[mt] = f4_t{ta.x, ta.y, ta.z, ta.w};
        bbR[mt] = f4_t{tb.x, tb.y, tb.z, tb.w};
    }

    const unsigned short* xb = x2 + (size_t)b * CHW_;
    const unsigned short* yb = y2b + (size_t)b * CHW_;
    unsigned short* dT = (s ? hn2 : hs2) + (size_t)b * CHW_;

    __shared__ __align__(16) unsigned short stt[2][16][72];

    int row0 = s ? 127 : 0;
    {
        const unsigned short* sp = xb + (size_t)(row0 * 128 + w0 + n) * 64 + q * 16;
        uint4 v0 = *(const uint4*)sp;
        uint4 v1 = *(const uint4*)(sp + 8);
        if (s) { v0 = relu8(v0); v1 = relu8(v1); }
        *(uint4*)&stt[0][n][q * 16] = v0;
        *(uint4*)&stt[0][n][q * 16 + 8] = v1;
        // WHC write
        unsigned short* op = dT + ((size_t)(w0 + n) * 128 + row0) * 64 + q * 16;
        *(uint4*)op = v0;
        *(uint4*)(op + 8) = v1;
    }

    // prefetch i=1
    uint4 xf0, xf1; ushort4 yv[4];
    {
        int row1 = s ? 126 : 1;
        const unsigned short* sp = xb + (size_t)(row1 * 128 + w0 + n) * 64 + q * 8;
        xf0 = *(const uint4*)sp;
        xf1 = *(const uint4*)(sp + 32);
#pragma unroll
        for (int mt = 0; mt < 4; mt++)
            yv[mt] = *(const ushort4*)&yb[(size_t)(row0 * 128 + w0 + n) * 64 + mt * 16 + q * 4];
    }
    WAVE_LDS_FENCE();

    for (int i = 1; i < 128; i++) {
        int row = s ? 127 - i : i;
        int rd = (i - 1) & 1, wr = i & 1;

        bfrag fb0 = *(const bfrag*)&stt[rd][n][q * 8];
        bfrag fb1 = *(const bfrag*)&stt[rd][n][32 + q * 8];
        bfrag fa0 = *(const bfrag*)&xf0;
        bfrag fa1 = *(const bfrag*)&xf1;

        // early prefetch of step i+1 inputs
        uint4 xn0, xn1; ushort4 yn[4];
        if (i < 127) {
            int rowN = s ? 127 - (i + 1) : i + 1;
            int yrowN = s ? rowN + 1 : rowN - 1;
            const unsigned short* sp = xb + (size_t)(rowN * 128 + w0 + n) * 64 + q * 8;
            xn0 = *(const uint4*)sp;
            xn1 = *(const uint4*)(sp + 32);
#pragma unroll
            for (int mt = 0; mt < 4; mt++)
                yn[mt] = *(const ushort4*)&yb[(size_t)(yrowN * 128 + w0 + n) * 64 + mt * 16 + q * 4];
        }

        f4_t DA[4], DB[4];
#pragma unroll
        for (int mt = 0; mt < 4; mt++) {
            DA[mt] = MFMA(WaF[mt][0], fa0, baR[mt], 0, 0, 0);
            DA[mt] = MFMA(WaF[mt][1], fa1, DA[mt], 0, 0, 0);
            DB[mt] = MFMA(WbF[mt][0], fb0, bbR[mt], 0, 0, 0);
            DB[mt] = MFMA(WbF[mt][1], fb1, DB[mt], 0, 0, 0);
        }

#pragma unroll
        for (int mt = 0; mt < 4; mt++) {
            float h0 = fmaxf(fmaf(DB[mt][0], b2f(yv[mt].x), DA[mt][0]), 0.f);
            float h1 = fmaxf(fmaf(DB[mt][1], b2f(yv[mt].y), DA[mt][1]), 0.f);
            float h2 = fmaxf(fmaf(DB[mt][2], b2f(yv[mt].z), DA[mt][2]), 0.f);
            float h3 = fmaxf(fmaf(DB[mt][3], b2f(yv[mt].w), DA[mt][3]), 0.f);
            uint2 pk; pk.x = cvtpk(h0, h1); pk.y = cvtpk(h2, h3);
            *(uint2*)&stt[wr][n][mt * 16 + q * 4] = pk;
            // WHC write
            *(uint2*)&dT[((size_t)(w0 + n) * 128 + row) * 64 + mt * 16 + q * 4] = pk;
        }
        if (i < 127) {
            xf0 = xn0; xf1 = xn1;
#pragma unroll
            for (int mt = 0; mt < 4; mt++) yv[mt] = yn[mt];
        }
        WAVE_LDS_FENCE();
    }
}

// Col scans: grid 32 = d(4) x b(8). 512 threads = 8 waves.
// base (WHC) + y (WHC channel-swizzled) -> all global loads perfectly
// coalesced 16B; state in swizzled LDS dbuf; reload-after-use pipeline.
__global__ __launch_bounds__(512, 2) void k_colscan(
        const unsigned short* __restrict__ y2t,
        const unsigned short* __restrict__ hs2, const unsigned short* __restrict__ hn2,
        const float* __restrict__ Wc, const float* __restrict__ bc,
        const float* __restrict__ gam,
        unsigned short* __restrict__ outD) {
    int bid = blockIdx.x;
    int d = bid >> 3, b = bid & 7;
    int tid = threadIdx.x;
    int wave = tid >> 6, lane = tid & 63, q = lane >> 4, n = lane & 15;
    int row = wave * 16 + n;
    int down = (d < 2) ? 1 : 0;
    int flip = d & 1;
    const unsigned short* base2 = ((d < 2) ? hs2 : hn2) + (size_t)b * CHW_;
    int kt, ka, kb;
    if (d == 0)      { kt = 2;  ka = 3;  kb = 4;  }
    else if (d == 1) { kt = 5;  ka = 6;  kb = 7;  }
    else if (d == 2) { kt = 10; ka = 11; kb = 12; }
    else             { kt = 13; ka = 14; kb = 15; }
    float g = gam[d];

    bfrag WA[4][2], WB[4][2], WT[4][2];
#pragma unroll
    for (int mt = 0; mt < 4; mt++)
#pragma unroll
        for (int kc = 0; kc < 2; kc++) {
            const float* wa = Wc + (size_t)(ka * 64 + mt * 16 + n) * 64 + kc * 32 + q * 8;
            const float* wb = Wc + (size_t)(kb * 64 + mt * 16 + n) * 64 + kc * 32 + q * 8;
            const float* wt = Wc + (size_t)(kt * 64 + mt * 16 + n) * 64 + kc * 32 + q * 8;
            WA[mt][kc] = packf(*(const float4*)wa, *(const float4*)(wa + 4));
            WB[mt][kc] = packf(*(const float4*)wb, *(const float4*)(wb + 4));
            WT[mt][kc] = packfs(*(const float4*)wt, *(const float4*)(wt + 4), g);
        }
    bool bz = down ? (row == 0) : (row == 127);
    f4_t bAr[4], bBr[4], bTr[4];
#pragma unroll
    for (int mt = 0; mt < 4; mt++) {
        float4 ta = *(const float4*)&bc[ka * 64 + mt * 16 + q * 4];
        float4 tb = *(const float4*)&bc[kb * 64 + mt * 16 + q * 4];
        float4 tt = *(const float4*)&bc[kt * 64 + mt * 16 + q * 4];
        bAr[mt] = f4_t{ta.x, ta.y, ta.z, ta.w};
        bBr[mt] = f4_t{tb.x, tb.y, tb.z, tb.w};
        float gm = bz ? 0.f : g;
        bTr[mt] = f4_t{gm * tt.x, gm * tt.y, gm * tt.z, gm * tt.w};
    }

    const unsigned short* yB = y2t + (size_t)b * CHW_;
    unsigned short* oB = outD + (size_t)d * TOT_ + (size_t)b * CHW_;

    __shared__ __align__(16) unsigned short stt[2][130][64];
    for (int idx = tid; idx < 2 * 2 * 64; idx += 512) {
        int buf = idx >> 7, hi = (idx >> 6) & 1, t = idx & 63;
        stt[buf][hi ? 129 : 0][t] = 0;
    }

    // ---- j = 0 : c0 = relu(base col0)   (base is WHC: column contiguous)
    int c0 = flip ? 127 : 0;
    {
        const unsigned short* sp = base2 + (size_t)c0 * 8192 + row * 64 + q * 16;
        uint4 v0 = relu8(*(const uint4*)sp);
        uint4 v1 = relu8(*(const uint4*)(sp + 8));
        *(uint4*)&stt[0][row + 1][swz(row + 1, q * 16)] = v0;
        *(uint4*)&stt[0][row + 1][swz(row + 1, q * 16 + 8)] = v1;
        unsigned short* op = oB + (size_t)(row * 128 + c0) * 64 + q * 16;
        *(uint4*)op = v0;
        *(uint4*)(op + 8) = v1;
    }

    int srow = down ? row : row + 2;
    int rsh = row + (down ? -1 : 1);
    rsh = rsh < 0 ? 0 : (rsh > 127 ? 127 : rsh);

    // initial loads for step 1: pb = base col c(1); yr/ys = y col yc(1)
    uint4 pb0, pb1, yr0, yr1, ys0, ys1;
    {
        int c1 = flip ? 126 : 1;
        const unsigned short* sp = base2 + (size_t)c1 * 8192 + row * 64 + q * 8;
        pb0 = *(const uint4*)sp;
        pb1 = *(const uint4*)(sp + 32);
        int yc1 = flip ? 127 : 0;
        const unsigned short* yp = yB + (size_t)yc1 * 8192 + row * 64 + q * 16;
        yr0 = *(const uint4*)yp;
        yr1 = *(const uint4*)(yp + 8);
        const unsigned short* yps = yB + (size_t)yc1 * 8192 + rsh * 64 + q * 16;
        ys0 = *(const uint4*)yps;
        ys1 = *(const uint4*)(yps + 8);
    }
    LDS_BARRIER();

    for (int j = 1; j < 128; j++) {
        int cj = flip ? 127 - j : j;
        int rd = (j - 1) & 1, wr = j & 1;

        bfrag fb0 = *(const bfrag*)&stt[rd][row + 1][swz(row + 1, q * 8)];
        bfrag fb1 = *(const bfrag*)&stt[rd][row + 1][swz(row + 1, 32 + q * 8)];
        bfrag ft0 = *(const bfrag*)&stt[rd][srow][swz(srow, q * 8)];
        bfrag ft1 = *(const bfrag*)&stt[rd][srow][swz(srow, 32 + q * 8)];
        bfrag fa0 = *(const bfrag*)&pb0;
        bfrag fa1 = *(const bfrag*)&pb1;

        f4_t DA[4], DB[4], DT[4];
#pragma unroll
        for (int mt = 0; mt < 4; mt++) {
            DA[mt] = MFMA(WA[mt][0], fa0, bAr[mt], 0, 0, 0);
            DA[mt] = MFMA(WA[mt][1], fa1, DA[mt], 0, 0, 0);
            DB[mt] = MFMA(WB[mt][0], fb0, bBr[mt], 0, 0, 0);
            DB[mt] = MFMA(WB[mt][1], fb1, DB[mt], 0, 0, 0);
            DT[mt] = MFMA(WT[mt][0], ft0, bTr[mt], 0, 0, 0);
            DT[mt] = MFMA(WT[mt][1], ft1, DT[mt], 0, 0, 0);
        }

        // y values for THIS step (loaded >=1 step ago)
        unsigned int yrw[8] = {yr0.x, yr0.y, yr0.z, yr0.w, yr1.x, yr1.y, yr1.z, yr1.w};
        unsigned int ysw[8] = {ys0.x, ys0.y, ys0.z, ys0.w, ys1.x, ys1.y, ys1.z, ys1.w};

        // reload pb <- base col c(j+1) right after consumption
        if (j < 127) {
            int cN = flip ? 126 - j : j + 1;
            const unsigned short* sp = base2 + (size_t)cN * 8192 + row * 64 + q * 8;
            pb0 = *(const uint4*)sp;
            pb1 = *(const uint4*)(sp + 32);
        }

        // finalize: h = relu(DA + DB*yr + DT*ys)
#pragma unroll
        for (int mt = 0; mt < 4; mt++) {
            unsigned int ur0 = yrw[2 * mt], ur1 = yrw[2 * mt + 1];
            unsigned int us0 = ysw[2 * mt], us1 = ysw[2 * mt + 1];
            float h0 = fmaxf(fmaf(DT[mt][0], blo(us0), fmaf(DB[mt][0], blo(ur0), DA[mt][0])), 0.f);
            float h1 = fmaxf(fmaf(DT[mt][1], bhi(us0), fmaf(DB[mt][1], bhi(ur0), DA[mt][1])), 0.f);
            float h2 = fmaxf(fmaf(DT[mt][2], blo(us1), fmaf(DB[mt][2], blo(ur1), DA[mt][2])), 0.f);
            float h3 = fmaxf(fmaf(DT[mt][3], bhi(us1), fmaf(DB[mt][3], bhi(ur1), DA[mt][3])), 0.f);
            uint2 pk; pk.x = cvtpk(h0, h1); pk.y = cvtpk(h2, h3);
            *(uint2*)&stt[wr][row + 1][swz(row + 1, mt * 16 + q * 4)] = pk;
            *(uint2*)&oB[(size_t)(row * 128 + cj) * 64 + mt * 16 + q * 4] = pk;
        }

        // reload yr/ys <- y col yc(j+1) right after consumption
        if (j < 127) {
            int ycN = flip ? 127 - j : j;
            const unsigned short* yp = yB + (size_t)ycN * 8192 + row * 64 + q * 16;
            yr0 = *(const uint4*)yp;
            yr1 = *(const uint4*)(yp + 8);
            const unsigned short* yps = yB + (size_t)ycN * 8192 + rsh * 64 + q * 16;
            ys0 = *(const uint4*)yps;
            ys1 = *(const uint4*)(yps + 8);
        }
        LDS_BARRIER();
    }
}

extern "C" void kernel_launch(void* const* d_in, const int* in_sizes, int n_in,
                              void* d_out, int out_size, void* d_ws, size_t ws_size,
                              hipStream_t stream) {
    const float* x   = (const float*)d_in[0];
    const float* y   = (const float*)d_in[1];
    const float* Wc  = (const float*)d_in[2];
    const float* bc  = (const float*)d_in[3];
    const float* gam = (const float*)d_in[4];
    float* out = (float*)d_out;

    // ws (all bf16): x2, y2b, y2t, hs2, hn2 (TOT_ each), outD (4x TOT_) = 151MB
    unsigned short* x2   = (unsigned short*)d_ws;
    unsigned short* y2b  = x2 + (size_t)TOT_;
    unsigned short* y2t  = y2b + (size_t)TOT_;
    unsigned short* hs2  = y2t + (size_t)TOT_;
    unsigned short* hn2  = hs2 + (size_t)TOT_;
    unsigned short* outD = hn2 + (size_t)TOT_;

    hipLaunchKernelGGL(k_prep, dim3(4096), dim3(256), 0, stream, x, y, y2b, x2, y2t);
    hipLaunchKernelGGL(k_rowscan, dim3(128), dim3(64), 0, stream, x2, y2b, Wc, bc, hs2, hn2);
    hipLaunchKernelGGL(k_colscan, dim3(32), dim3(512), 0, stream, y2t, hs2, hn2, Wc, bc, gam, outD);
    hipLaunchKernelGGL(k_tb, dim3(2048), dim3(256), 0, stream,
                       outD, outD + (size_t)TOT_, outD + 2 * (size_t)TOT_,
                       outD + 3 * (size_t)TOT_, out);
}

// Round 7
// 507.475 us; speedup vs baseline: 1.3804x; 1.0173x over previous
//
#include <hip/hip_runtime.h>

// UAG_RNN v11: v10 + scan-loop restructure (no layout changes).
//  - colscan: step split around the barrier. fb (own-wave state) + DA/DB MFMAs
//    + pb reload run PRE-barrier (only ft, the 1-row cross-wave shifted state,
//    needs the barrier). Post-barrier: ft read + DT + finalize.
//  - store-gating fix: y reloads for j+1 are issued BEFORE the oB stores so
//    the in-order vmcnt wait for y next step no longer drains store-acks.
//  - consume-then-reload everywhere (no register copies of in-flight loads).
//  - rowscan: same reorder (x reload after MFMA, y reload after h-compute,
//    stores last). WAVE_LDS_FENCE orders own stt write->read.
// B=8, C=64, H=128, W=128.

#define B_ 8
#define C_ 64
#define H_ 128
#define W_ 128
#define HW_ (H_*W_)      // 16384
#define CHW_ (C_*HW_)    // 1048576
#define TOT_ (B_*CHW_)   // 8388608

typedef __attribute__((ext_vector_type(8))) short bfrag;
typedef __attribute__((ext_vector_type(4))) float f4_t;

// Fused LDS-ordering barrier: waitcnt+barrier in ONE asm blob so nothing can
// be scheduled between them; "memory" clobber pins IR-level motion;
// sched_barrier(0) pins machine-scheduler motion. Does NOT drain vmcnt.
#define LDS_BARRIER() do { \
    __builtin_amdgcn_sched_barrier(0); \
    asm volatile("s_waitcnt lgkmcnt(0)\n\ts_barrier" ::: "memory"); \
    __builtin_amdgcn_sched_barrier(0); \
} while (0)

// Wave-level LDS ordering point (own-data write->read across iterations).
#define WAVE_LDS_FENCE() do { \
    asm volatile("s_waitcnt lgkmcnt(0)" ::: "memory"); \
    __builtin_amdgcn_sched_barrier(0); \
} while (0)

__device__ inline unsigned short bfr(float f) {
    unsigned int u = __float_as_uint(f);
    u += 0x7fffu + ((u >> 16) & 1u);
    return (unsigned short)(u >> 16);
}
__device__ inline float b2f(unsigned short u) {
    return __uint_as_float(((unsigned int)u) << 16);
}
__device__ inline float blo(unsigned int u) { return __uint_as_float(u << 16); }
__device__ inline float bhi(unsigned int u) { return __uint_as_float(u & 0xffff0000u); }
// HW packed f32->bf16 (RNE, identical to bfr)
__device__ inline unsigned int cvtpk(float lo, float hi) {
    unsigned int r;
    asm("v_cvt_pk_bf16_f32 %0, %1, %2" : "=v"(r) : "v"(lo), "v"(hi));
    return r;
}
__device__ inline bfrag packf(float4 a, float4 b) {
    bfrag r;
    r[0]=(short)bfr(a.x); r[1]=(short)bfr(a.y); r[2]=(short)bfr(a.z); r[3]=(short)bfr(a.w);
    r[4]=(short)bfr(b.x); r[5]=(short)bfr(b.y); r[6]=(short)bfr(b.z); r[7]=(short)bfr(b.w);
    return r;
}
__device__ inline bfrag packfs(float4 a, float4 b, float s) {
    bfrag r;
    r[0]=(short)bfr(s*a.x); r[1]=(short)bfr(s*a.y); r[2]=(short)bfr(s*a.z); r[3]=(short)bfr(s*a.w);
    r[4]=(short)bfr(s*b.x); r[5]=(short)bfr(s*b.y); r[6]=(short)bfr(s*b.z); r[7]=(short)bfr(s*b.w);
    return r;
}
__device__ inline unsigned int relu2(unsigned int w) {
    unsigned int lo = (w & 0x8000u) ? 0u : (w & 0xffffu);
    unsigned int hi = (w & 0x80000000u) ? 0u : (w & 0xffff0000u);
    return lo | hi;
}
__device__ inline uint4 relu8(uint4 v) {
    v.x = relu2(v.x); v.y = relu2(v.y); v.z = relu2(v.z); v.w = relu2(v.w);
    return v;
}
// XOR slot swizzle for stt (rows of 64 shorts = 8 slots of 16B)
__device__ inline int swz(int r, int s) {
    return (((s >> 3) ^ (r & 7)) << 3) | (s & 7);
}
// channel use-order swizzle for y2t: c = mt*16+q*4+r -> q*16+mt*4+r
__device__ inline int newc(int c) {
    return (((c >> 2) & 3) << 4) | ((c >> 4) << 2) | (c & 3);
}

#define MFMA __builtin_amdgcn_mfma_f32_16x16x32_bf16

// x NCHW fp32 -> x2 NHWC bf16; y NCHW fp32 -> y2b NHWC bf16 + y2t WHC-swz bf16
__global__ void k_prep(const float* __restrict__ x, const float* __restrict__ y,
                       unsigned short* __restrict__ y2b, unsigned short* __restrict__ x2,
                       unsigned short* __restrict__ y2t) {
    __shared__ float t[64][65];
    int blk = blockIdx.x;
    int isx = blk >> 11; blk &= 2047;
    int b = blk >> 8, hw0 = (blk & 255) * 64;
    int cq = threadIdx.x >> 6, lo = threadIdx.x & 63;
    const float* ip = (isx ? x : y) + (size_t)b * CHW_;
#pragma unroll
    for (int p = 0; p < 16; p++) {
        int c = p * 4 + cq;
        t[c][lo] = ip[(size_t)c * HW_ + hw0 + lo];
    }
    __syncthreads();
    unsigned short* op = (isx ? x2 : y2b) + (size_t)b * CHW_;
#pragma unroll
    for (int p = 0; p < 16; p++) {
        int hw = p * 4 + cq;
        op[(size_t)(hw0 + hw) * 64 + lo] = bfr(t[lo][hw]);
    }
    if (!isx) {
        unsigned short* op2 = y2t + (size_t)b * CHW_;
        int lon = newc(lo);
#pragma unroll
        for (int p = 0; p < 16; p++) {
            int hw = p * 4 + cq;
            int pos = hw0 + hw, h = pos >> 7, w = pos & 127;
            op2[(size_t)w * 8192 + h * 64 + lon] = bfr(t[lo][hw]);
        }
    }
}

// sum 4 bf16 NHWC dir buffers -> out NCHW fp32
__global__ void k_tb(const unsigned short* __restrict__ i0, const unsigned short* __restrict__ i1,
                     const unsigned short* __restrict__ i2, const unsigned short* __restrict__ i3,
                     float* __restrict__ outp) {
    __shared__ float t[64][65];
    int blk = blockIdx.x;
    int b = blk >> 8, hw0 = (blk & 255) * 64;
    int tid = threadIdx.x;
    size_t bb = (size_t)b * CHW_;
    int hwi = tid >> 4, c4 = (tid & 15) * 4;
#pragma unroll
    for (int p = 0; p < 4; p++) {
        int hw = p * 16 + hwi;
        size_t s = bb + (size_t)(hw0 + hw) * 64 + c4;
        uint2 u0 = *(const uint2*)(i0 + s);
        uint2 u1 = *(const uint2*)(i1 + s);
        uint2 u2 = *(const uint2*)(i2 + s);
        uint2 u3 = *(const uint2*)(i3 + s);
        float v0 = blo(u0.x) + blo(u1.x) + blo(u2.x) + blo(u3.x);
        float v1 = bhi(u0.x) + bhi(u1.x) + bhi(u2.x) + bhi(u3.x);
        float v2 = blo(u0.y) + blo(u1.y) + blo(u2.y) + blo(u3.y);
        float v3 = bhi(u0.y) + bhi(u1.y) + bhi(u2.y) + bhi(u3.y);
        t[hw][c4 + 0] = v0; t[hw][c4 + 1] = v1; t[hw][c4 + 2] = v2; t[hw][c4 + 3] = v3;
    }
    __syncthreads();
    float* op = outp + bb;
    int cq = tid >> 6, lo = tid & 63;
#pragma unroll
    for (int p = 0; p < 16; p++) {
        int c = p * 4 + cq;
        op[(size_t)c * HW_ + hw0 + lo] = t[lo][c];
    }
}

// Row scans: grid 128 = s(2) x b(8) x wb(8 of width 16). 1 wave/block.
// dT written in [W][H][C] layout for colscan.
__global__ __launch_bounds__(64) void k_rowscan(
        const unsigned short* __restrict__ x2, const unsigned short* __restrict__ y2b,
        const float* __restrict__ Wc, const float* __restrict__ bc,
        unsigned short* __restrict__ hs2, unsigned short* __restrict__ hn2) {
    int bid = blockIdx.x;
    int s = bid >> 6, b = (bid >> 3) & 7, wb = bid & 7;
    int w0 = wb * 16;
    int lane = threadIdx.x, q = lane >> 4, n = lane & 15;
    int ka = s ? 8 : 0, kb = ka + 1;

    bfrag WaF[4][2], WbF[4][2];
#pragma unroll
    for (int mt = 0; mt < 4; mt++)
#pragma unroll
        for (int kc = 0; kc < 2; kc++) {
            const float* wp = Wc + (size_t)(ka * 64 + mt * 16 + n) * 64 + kc * 32 + q * 8;
            WaF[mt][kc] = packf(*(const float4*)wp, *(const float4*)(wp + 4));
            const float* wq2 = Wc + (size_t)(kb * 64 + mt * 16 + n) * 64 + kc * 32 + q * 8;
            WbF[mt][kc] = packf(*(const float4*)wq2, *(const float4*)(wq2 + 4));
        }
    f4_t baR[4], bbR[4];
#pragma unroll
    for (int mt = 0; mt < 4; mt++) {
        float4 ta = *(const float4*)&bc[ka * 64 + mt * 16 + q * 4];
        float4 tb = *(const float4*)&bc[kb * 64 + mt * 16 + q * 4];
        baR[mt] = f4_t{ta.x, ta.y, ta.z, ta.w};
        bbR[mt] = f4_t{tb.x, tb.y, tb.z, tb.w};
    }

    const unsigned short* xb = x2 + (size_t)b * CHW_;
    const unsigned short* yb = y2b + (size_t)b * CHW_;
    unsigned short* dT = (s ? hn2 : hs2) + (size_t)b * CHW_;

    __shared__ __align__(16) unsigned short stt[2][16][72];

    int row0 = s ? 127 : 0;
    {
        const unsigned short* sp = xb + (size_t)(row0 * 128 + w0 + n) * 64 + q * 16;
        uint4 v0 = *(const uint4*)sp;
        uint4 v1 = *(const uint4*)(sp + 8);
        if (s) { v0 = relu8(v0); v1 = relu8(v1); }
        *(uint4*)&stt[0][n][q * 16] = v0;
        *(uint4*)&stt[0][n][q * 16 + 8] = v1;
        // WHC write
        unsigned short* op = dT + ((size_t)(w0 + n) * 128 + row0) * 64 + q * 16;
        *(uint4*)op = v0;
        *(uint4*)(op + 8) = v1;
    }

    // prefetch i=1
    uint4 xf0, xf1; ushort4 yv[4];
    {
        int row1 = s ? 126 : 1;
        const unsigned short* sp = xb + (size_t)(row1 * 128 + w0 + n) * 64 + q * 8;
        xf0 = *(const uint4*)sp;
        xf1 = *(const uint4*)(sp + 32);
#pragma unroll
        for (int mt = 0; mt < 4; mt++)
            yv[mt] = *(const ushort4*)&yb[(size_t)(row0 * 128 + w0 + n) * 64 + mt * 16 + q * 4];
    }
    WAVE_LDS_FENCE();

    for (int i = 1; i < 128; i++) {
        int row = s ? 127 - i : i;
        int rd = (i - 1) & 1, wr = i & 1;

        bfrag fb0 = *(const bfrag*)&stt[rd][n][q * 8];
        bfrag fb1 = *(const bfrag*)&stt[rd][n][32 + q * 8];
        bfrag fa0 = *(const bfrag*)&xf0;
        bfrag fa1 = *(const bfrag*)&xf1;

        f4_t DA[4], DB[4];
#pragma unroll
        for (int mt = 0; mt < 4; mt++) {
            DA[mt] = MFMA(WaF[mt][0], fa0, baR[mt], 0, 0, 0);
            DA[mt] = MFMA(WaF[mt][1], fa1, DA[mt], 0, 0, 0);
            DB[mt] = MFMA(WbF[mt][0], fb0, bbR[mt], 0, 0, 0);
            DB[mt] = MFMA(WbF[mt][1], fb1, DB[mt], 0, 0, 0);
        }

        // reload x for i+1 right after consumption (no copies)
        if (i < 127) {
            int rowN = s ? 127 - (i + 1) : i + 1;
            const unsigned short* sp = xb + (size_t)(rowN * 128 + w0 + n) * 64 + q * 8;
            xf0 = *(const uint4*)sp;
            xf1 = *(const uint4*)(sp + 32);
        }

        // h-compute consumes yv (loaded last iter)
        float h[4][4];
#pragma unroll
        for (int mt = 0; mt < 4; mt++) {
            h[mt][0] = fmaxf(fmaf(DB[mt][0], b2f(yv[mt].x), DA[mt][0]), 0.f);
            h[mt][1] = fmaxf(fmaf(DB[mt][1], b2f(yv[mt].y), DA[mt][1]), 0.f);
            h[mt][2] = fmaxf(fmaf(DB[mt][2], b2f(yv[mt].z), DA[mt][2]), 0.f);
            h[mt][3] = fmaxf(fmaf(DB[mt][3], b2f(yv[mt].w), DA[mt][3]), 0.f);
        }

        // reload y for i+1 BEFORE the stores (no store-gating next iter)
        if (i < 127) {
            int rowN = s ? 127 - (i + 1) : i + 1;
            int yrowN = s ? rowN + 1 : rowN - 1;
#pragma unroll
            for (int mt = 0; mt < 4; mt++)
                yv[mt] = *(const ushort4*)&yb[(size_t)(yrowN * 128 + w0 + n) * 64 + mt * 16 + q * 4];
        }

        // pack + state write + output store
#pragma unroll
        for (int mt = 0; mt < 4; mt++) {
            uint2 pk; pk.x = cvtpk(h[mt][0], h[mt][1]); pk.y = cvtpk(h[mt][2], h[mt][3]);
            *(uint2*)&stt[wr][n][mt * 16 + q * 4] = pk;
            *(uint2*)&dT[((size_t)(w0 + n) * 128 + row) * 64 + mt * 16 + q * 4] = pk;
        }
        WAVE_LDS_FENCE();
    }
}

// Col scans: grid 32 = d(4) x b(8). 512 threads = 8 waves.
// Step split around the barrier: fb (own rows) + DA/DB pre-barrier; only ft
// (cross-wave shifted row) + DT + finalize post-barrier. y reloads issued
// before oB stores (no in-order-vmcnt store-gating).
__global__ __launch_bounds__(512, 2) void k_colscan(
        const unsigned short* __restrict__ y2t,
        const unsigned short* __restrict__ hs2, const unsigned short* __restrict__ hn2,
        const float* __restrict__ Wc, const float* __restrict__ bc,
        const float* __restrict__ gam,
        unsigned short* __restrict__ outD) {
    int bid = blockIdx.x;
    int d = bid >> 3, b = bid & 7;
    int tid = threadIdx.x;
    int wave = tid >> 6, lane = tid & 63, q = lane >> 4, n = lane & 15;
    int row = wave * 16 + n;
    int down = (d < 2) ? 1 : 0;
    int flip = d & 1;
    const unsigned short* base2 = ((d < 2) ? hs2 : hn2) + (size_t)b * CHW_;
    int kt, ka, kb;
    if (d == 0)      { kt = 2;  ka = 3;  kb = 4;  }
    else if (d == 1) { kt = 5;  ka = 6;  kb = 7;  }
    else if (d == 2) { kt = 10; ka = 11; kb = 12; }
    else             { kt = 13; ka = 14; kb = 15; }
    float g = gam[d];

    bfrag WA[4][2], WB[4][2], WT[4][2];
#pragma unroll
    for (int mt = 0; mt < 4; mt++)
#pragma unroll
        for (int kc = 0; kc < 2; kc++) {
            const float* wa = Wc + (size_t)(ka * 64 + mt * 16 + n) * 64 + kc * 32 + q * 8;
            const float* wb = Wc + (size_t)(kb * 64 + mt * 16 + n) * 64 + kc * 32 + q * 8;
            const float* wt = Wc + (size_t)(kt * 64 + mt * 16 + n) * 64 + kc * 32 + q * 8;
            WA[mt][kc] = packf(*(const float4*)wa, *(const float4*)(wa + 4));
            WB[mt][kc] = packf(*(const float4*)wb, *(const float4*)(wb + 4));
            WT[mt][kc] = packfs(*(const float4*)wt, *(const float4*)(wt + 4), g);
        }
    bool bz = down ? (row == 0) : (row == 127);
    f4_t bAr[4], bBr[4], bTr[4];
#pragma unroll
    for (int mt = 0; mt < 4; mt++) {
        float4 ta = *(const float4*)&bc[ka * 64 + mt * 16 + q * 4];
        float4 tb = *(const float4*)&bc[kb * 64 + mt * 16 + q * 4];
        float4 tt = *(const float4*)&bc[kt * 64 + mt * 16 + q * 4];
        bAr[mt] = f4_t{ta.x, ta.y, ta.z, ta.w};
        bBr[mt] = f4_t{tb.x, tb.y, tb.z, tb.w};
        float gm = bz ? 0.f : g;
        bTr[mt] = f4_t{gm * tt.x, gm * tt.y, gm * tt.z, gm * tt.w};
    }

    const unsigned short* yB = y2t + (size_t)b * CHW_;
    unsigned short* oB = outD + (size_t)d * TOT_ + (size_t)b * CHW_;

    __shared__ __align__(16) unsigned short stt[2][130][64];
    for (int idx = tid; idx < 2 * 2 * 64; idx += 512) {
        int buf = idx >> 7, hi = (idx >> 6) & 1, t = idx & 63;
        stt[buf][hi ? 129 : 0][t] = 0;
    }

    // ---- j = 0 : c0 = relu(base col0)   (base is WHC: column contiguous)
    int c0 = flip ? 127 : 0;
    {
        const unsigned short* sp = base2 + (size_t)c0 * 8192 + row * 64 + q * 16;
        uint4 v0 = relu8(*(const uint4*)sp);
        uint4 v1 = relu8(*(const uint4*)(sp + 8));
        *(uint4*)&stt[0][row + 1][swz(row + 1, q * 16)] = v0;
        *(uint4*)&stt[0][row + 1][swz(row + 1, q * 16 + 8)] = v1;
        unsigned short* op = oB + (size_t)(row * 128 + c0) * 64 + q * 16;
        *(uint4*)op = v0;
        *(uint4*)(op + 8) = v1;
    }

    int srow = down ? row : row + 2;
    int rsh = row + (down ? -1 : 1);
    rsh = rsh < 0 ? 0 : (rsh > 127 ? 127 : rsh);

    // initial loads for step 1: pb = base col c(1); yr/ys = y col yc(1)
    uint4 pb0, pb1, yr0, yr1, ys0, ys1;
    {
        int c1 = flip ? 126 : 1;
        const unsigned short* sp = base2 + (size_t)c1 * 8192 + row * 64 + q * 8;
        pb0 = *(const uint4*)sp;
        pb1 = *(const uint4*)(sp + 32);
        int yc1 = flip ? 127 : 0;
        const unsigned short* yp = yB + (size_t)yc1 * 8192 + row * 64 + q * 16;
        yr0 = *(const uint4*)yp;
        yr1 = *(const uint4*)(yp + 8);
        const unsigned short* yps = yB + (size_t)yc1 * 8192 + rsh * 64 + q * 16;
        ys0 = *(const uint4*)yps;
        ys1 = *(const uint4*)(yps + 8);
    }
    LDS_BARRIER();

    for (int j = 1; j < 128; j++) {
        int cj = flip ? 127 - j : j;
        int rd = (j - 1) & 1, wr = j & 1;

        // ---- PRE-barrier zone: own-wave state + DA/DB
        bfrag fb0 = *(const bfrag*)&stt[rd][row + 1][swz(row + 1, q * 8)];
        bfrag fb1 = *(const bfrag*)&stt[rd][row + 1][swz(row + 1, 32 + q * 8)];
        bfrag fa0 = *(const bfrag*)&pb0;
        bfrag fa1 = *(const bfrag*)&pb1;

        f4_t DA[4], DB[4];
#pragma unroll
        for (int mt = 0; mt < 4; mt++) {
            DA[mt] = MFMA(WA[mt][0], fa0, bAr[mt], 0, 0, 0);
            DA[mt] = MFMA(WA[mt][1], fa1, DA[mt], 0, 0, 0);
            DB[mt] = MFMA(WB[mt][0], fb0, bBr[mt], 0, 0, 0);
            DB[mt] = MFMA(WB[mt][1], fb1, DB[mt], 0, 0, 0);
        }

        // reload pb <- base col c(j+1) right after consumption
        if (j < 127) {
            int cN = flip ? 126 - j : j + 1;
            const unsigned short* sp = base2 + (size_t)cN * 8192 + row * 64 + q * 8;
            pb0 = *(const uint4*)sp;
            pb1 = *(const uint4*)(sp + 32);
        }

        LDS_BARRIER();   // all waves' state(j-1) visible -> cross-wave ft safe

        // ---- POST-barrier: shifted state + DT
        bfrag ft0 = *(const bfrag*)&stt[rd][srow][swz(srow, q * 8)];
        bfrag ft1 = *(const bfrag*)&stt[rd][srow][swz(srow, 32 + q * 8)];
        f4_t DT[4];
#pragma unroll
        for (int mt = 0; mt < 4; mt++) {
            DT[mt] = MFMA(WT[mt][0], ft0, bTr[mt], 0, 0, 0);
            DT[mt] = MFMA(WT[mt][1], ft1, DT[mt], 0, 0, 0);
        }

        // h-compute consumes yr/ys (loaded last iter)
        unsigned int yrw[8] = {yr0.x, yr0.y, yr0.z, yr0.w, yr1.x, yr1.y, yr1.z, yr1.w};
        unsigned int ysw[8] = {ys0.x, ys0.y, ys0.z, ys0.w, ys1.x, ys1.y, ys1.z, ys1.w};
        float h[4][4];
#pragma unroll
        for (int mt = 0; mt < 4; mt++) {
            unsigned int ur0 = yrw[2 * mt], ur1 = yrw[2 * mt + 1];
            unsigned int us0 = ysw[2 * mt], us1 = ysw[2 * mt + 1];
            h[mt][0] = fmaxf(fmaf(DT[mt][0], blo(us0), fmaf(DB[mt][0], blo(ur0), DA[mt][0])), 0.f);
            h[mt][1] = fmaxf(fmaf(DT[mt][1], bhi(us0), fmaf(DB[mt][1], bhi(ur0), DA[mt][1])), 0.f);
            h[mt][2] = fmaxf(fmaf(DT[mt][2], blo(us1), fmaf(DB[mt][2], blo(ur1), DA[mt][2])), 0.f);
            h[mt][3] = fmaxf(fmaf(DT[mt][3], bhi(us1), fmaf(DB[mt][3], bhi(ur1), DA[mt][3])), 0.f);
        }

        // reload yr/ys <- y col yc(j+1) BEFORE any store (no store-gating)
        if (j < 127) {
            int ycN = flip ? 127 - j : j;
            const unsigned short* yp = yB + (size_t)ycN * 8192 + row * 64 + q * 16;
            yr0 = *(const uint4*)yp;
            yr1 = *(const uint4*)(yp + 8);
            const unsigned short* yps = yB + (size_t)ycN * 8192 + rsh * 64 + q * 16;
            ys0 = *(const uint4*)yps;
            ys1 = *(const uint4*)(yps + 8);
        }

        // pack + state write + output store
#pragma unroll
        for (int mt = 0; mt < 4; mt++) {
            uint2 pk; pk.x = cvtpk(h[mt][0], h[mt][1]); pk.y = cvtpk(h[mt][2], h[mt][3]);
            *(uint2*)&stt[wr][row + 1][swz(row + 1, mt * 16 + q * 4)] = pk;
            *(uint2*)&oB[(size_t)(row * 128 + cj) * 64 + mt * 16 + q * 4] = pk;
        }
        WAVE_LDS_FENCE();   // order own state write -> next iter's fb read
    }
}

extern "C" void kernel_launch(void* const* d_in, const int* in_sizes, int n_in,
                              void* d_out, int out_size, void* d_ws, size_t ws_size,
                              hipStream_t stream) {
    const float* x   = (const float*)d_in[0];
    const float* y   = (const float*)d_in[1];
    const float* Wc  = (const float*)d_in[2];
    const float* bc  = (const float*)d_in[3];
    const float* gam = (const float*)d_in[4];
    float* out = (float*)d_out;

    // ws (all bf16): x2, y2b, y2t, hs2, hn2 (TOT_ each), outD (4x TOT_) = 151MB
    unsigned short* x2   = (unsigned short*)d_ws;
    unsigned short* y2b  = x2 + (size_t)TOT_;
    unsigned short* y2t  = y2b + (size_t)TOT_;
    unsigned short* hs2  = y2t + (size_t)TOT_;
    unsigned short* hn2  = hs2 + (size_t)TOT_;
    unsigned short* outD = hn2 + (size_t)TOT_;

    hipLaunchKernelGGL(k_prep, dim3(4096), dim3(256), 0, stream, x, y, y2b, x2, y2t);
    hipLaunchKernelGGL(k_rowscan, dim3(128), dim3(64), 0, stream, x2, y2b, Wc, bc, hs2, hn2);
    hipLaunchKernelGGL(k_colscan, dim3(32), dim3(512), 0, stream, y2t, hs2, hn2, Wc, bc, gam, outD);
    hipLaunchKernelGGL(k_tb, dim3(2048), dim3(256), 0, stream,
                       outD, outD + (size_t)TOT_, outD + 2 * (size_t)TOT_,
                       outD + 3 * (size_t)TOT_, out);
}